// Round 7
// baseline (152.914 us; speedup 1.0000x reference)
//
#include <hip/hip_runtime.h>
#include <math.h>

// Problem constants
#define B_     4
#define N_     2048
#define H_     256
#define ROWS   8192    // B_*N_
#define EPS_   1e-8f
#define REGW   1e-5f
#define OUT_MAIN (ROWS*H_)   // 2097152

static __device__ __forceinline__ float elu1(float x) {
    return x > 0.f ? x + 1.f : __expf(x);
}

// stage + transpose a 256-row w_high chunk [256][24] -> dst[k*260 + j]
static __device__ __forceinline__ void stage_whT(
    const float* __restrict__ wsrc, float* __restrict__ dst, int t)
{
#pragma unroll
    for (int i = 0; i < 6; i++) {
        int g = t + i * 256;
        float4 v4 = *(const float4*)(wsrc + g * 4);
        int e = g * 4, j = e / 24, k = e - j * 24;
        dst[(k + 0) * 260 + j] = v4.x;
        dst[(k + 1) * 260 + j] = v4.y;
        dst[(k + 2) * 260 + j] = v4.z;
        dst[(k + 3) * 260 + j] = v4.w;
    }
}

// ---------------------------------------------------------------------------
// k1_qkv (ka_ql FUSED IN): grid 512 = b*128 + h*32 + ch; block = 64 rows of
// one head.  Phase A computes ql[24][64] for ITS OWN rows directly from x
// (register loads + 16-lane shfl reduce, 4 chunks of 16 rows) -- the
// ka_ql kernel, its launch gap, and the g_ql round-trip into k2 are gone
// (ql compute is duplicated across the 4 heads; +~150M MAC chip-wide,
// ~3-4us VALU -- cheaper than a launch).  h==0 blocks still export g_ql
// for k4's qf recompute.  Phase B (unchanged math from round-6 k2_kvz):
// kf (elu+1) / v tiles, z, 64-row partial kv -> kvp.  NO FENCES (round-5
// lesson: per-block device fences serialize on L2 writeback).
// LDS 53.25 KB (w_low region unioned with wkT/wvT/kfs/vss) -> 3 blocks/CU.
// ---------------------------------------------------------------------------
__global__ __launch_bounds__(256) void k1_qkv(
    const float* __restrict__ x, const float* __restrict__ w_low,
    const float* __restrict__ b_low, const float* __restrict__ w_high,
    const float* __restrict__ b_high, float* __restrict__ g_ql,
    float* __restrict__ zg, float* __restrict__ kvp,
    float* __restrict__ out)
{
    __shared__ float qls[24 * 64];     // [kk][r], persists A -> B
    __shared__ float big[11776];       // union buffer, 47.1 KB
    float* wlow = big;                 // phase A: [24][260] (6240 floats)
    float* wkT  = big;                 // phase B: [24][64]
    float* wvT  = big + 1536;          //          [24][64]
    float* kfs  = big + 3072;          //          [64][68]
    float* vss  = big + 7424;          //          [64][68]

    const int blk = blockIdx.x, t = threadIdx.x;
    const int b = blk >> 7, h = (blk >> 5) & 3, ch = blk & 31;
    const int rowb = b * N_ + ch * 64;

    if (blk == 0 && t == 0)
        out[OUT_MAIN] = REGW / (float)N_;   // reg-loss: softmax rows sum to 1
                                            // => mean|attn| = 1/N exactly

    // ---- phase A: ql for this block's 64 rows --------------------------
    // stage w_low [24][256] -> wlow[j*260+k]
#pragma unroll
    for (int i = 0; i < 6; i++) {
        int g = t + i * 256;
        int j = g >> 6, k = (g & 63) * 4;
        *(float4*)&wlow[j * 260 + k] = *(const float4*)(w_low + g * 4);
    }
    __syncthreads();

    const int rb = t >> 4, c4 = t & 15;
    for (int cc = 0; cc < 4; cc++) {
        const size_t row = (size_t)rowb + cc * 16 + rb;
        float4 xr[4];
#pragma unroll
        for (int i = 0; i < 4; i++)
            xr[i] = *(const float4*)(x + row * H_ + i * 64 + c4 * 4);
        float ql[24];
#pragma unroll
        for (int j = 0; j < 24; j++) {
            float s = 0.f;
#pragma unroll
            for (int i = 0; i < 4; i++) {
                float4 w4 = *(const float4*)&wlow[j * 260 + i * 64 + c4 * 4];
                s += xr[i].x * w4.x + xr[i].y * w4.y + xr[i].z * w4.z + xr[i].w * w4.w;
            }
            s += __shfl_xor(s, 1, 16);
            s += __shfl_xor(s, 2, 16);
            s += __shfl_xor(s, 4, 16);
            s += __shfl_xor(s, 8, 16);
            ql[j] = s + b_low[j];
        }
        // lane-owned entries, static selects (rule #20)
        float v1 = 0.f, v2 = 0.f;
#pragma unroll
        for (int j = 0; j < 16; j++) if (c4 == j) v1 = ql[j];
#pragma unroll
        for (int j = 0; j < 8; j++)  if (c4 == j) v2 = ql[16 + j];
        qls[c4 * 64 + cc * 16 + rb] = v1;
        if (c4 < 8) qls[(16 + c4) * 64 + cc * 16 + rb] = v2;
    }
    __syncthreads();   // qls complete; wlow dead

    // h==0 blocks export g_ql (col-major [kk][row]) for k4
    if (h == 0) {
#pragma unroll
        for (int i = 0; i < 2; i++) {
            int g = t + i * 256;
            if (g < 384) {
                int kk = g >> 4, r4 = g & 15;
                *(float4*)(g_ql + (size_t)kk * ROWS + rowb + r4 * 4) =
                    *(const float4*)&qls[kk * 64 + r4 * 4];
            }
        }
    }

    // ---- phase B: kf / v / z / partial kv (round-6 k2_kvz math) --------
    // stage head-slices of w_high, coalesced f4 + transpose.
    // k-chunk base: (256 + h*64)*24 = 6144 + h*1536 ; v: 12288 + h*1536.
#pragma unroll
    for (int i = 0; i < 2; i++) {
        int g = t + i * 256;
        if (g < 384) {
            float4 a4 = *(const float4*)(w_high + 6144 + h * 1536 + g * 4);
            float4 b4 = *(const float4*)(w_high + 12288 + h * 1536 + g * 4);
            int e = g * 4, d = e / 24, kk = e - d * 24;
            wkT[(kk + 0) * 64 + d] = a4.x;
            wkT[(kk + 1) * 64 + d] = a4.y;
            wkT[(kk + 2) * 64 + d] = a4.z;
            wkT[(kk + 3) * 64 + d] = a4.w;
            wvT[(kk + 0) * 64 + d] = b4.x;
            wvT[(kk + 1) * 64 + d] = b4.y;
            wvT[(kk + 2) * 64 + d] = b4.z;
            wvT[(kk + 3) * 64 + d] = b4.w;
        }
    }
    __syncthreads();

    const int gR = t >> 4;   // 16 row-groups(4 rows) x 16 col-quads (c4)

    // kf tile (+ z): rows gR*4..+3, cols c4*4..+3
    {
        float4 bh4 = *(const float4*)(b_high + 256 + h * 64 + c4 * 4);
        float4 acc[4];
#pragma unroll
        for (int rr = 0; rr < 4; rr++) acc[rr] = bh4;
#pragma unroll
        for (int kk = 0; kk < 24; kk++) {
            float4 w4 = *(const float4*)&wkT[kk * 64 + c4 * 4];
            float4 qa = *(const float4*)&qls[kk * 64 + gR * 4];
            acc[0].x += qa.x * w4.x; acc[0].y += qa.x * w4.y; acc[0].z += qa.x * w4.z; acc[0].w += qa.x * w4.w;
            acc[1].x += qa.y * w4.x; acc[1].y += qa.y * w4.y; acc[1].z += qa.y * w4.z; acc[1].w += qa.y * w4.w;
            acc[2].x += qa.z * w4.x; acc[2].y += qa.z * w4.y; acc[2].z += qa.z * w4.z; acc[2].w += qa.z * w4.w;
            acc[3].x += qa.w * w4.x; acc[3].y += qa.w * w4.y; acc[3].z += qa.w * w4.z; acc[3].w += qa.w * w4.w;
        }
#pragma unroll
        for (int rr = 0; rr < 4; rr++) {
            float4 a = acc[rr];
            a.x = elu1(a.x); a.y = elu1(a.y); a.z = elu1(a.z); a.w = elu1(a.w);
            *(float4*)&kfs[(gR * 4 + rr) * 68 + c4 * 4] = a;
            float s = a.x + a.y + a.z + a.w;
            s += __shfl_xor(s, 1, 16);
            s += __shfl_xor(s, 2, 16);
            s += __shfl_xor(s, 4, 16);
            s += __shfl_xor(s, 8, 16);
            if (c4 == 0)
                zg[(size_t)(rowb + gR * 4 + rr) * 4 + h] = 1.f / (s + EPS_);
        }
    }
    // v tile
    {
        float4 bh4 = *(const float4*)(b_high + 512 + h * 64 + c4 * 4);
        float4 acc[4];
#pragma unroll
        for (int rr = 0; rr < 4; rr++) acc[rr] = bh4;
#pragma unroll
        for (int kk = 0; kk < 24; kk++) {
            float4 w4 = *(const float4*)&wvT[kk * 64 + c4 * 4];
            float4 qa = *(const float4*)&qls[kk * 64 + gR * 4];
            acc[0].x += qa.x * w4.x; acc[0].y += qa.x * w4.y; acc[0].z += qa.x * w4.z; acc[0].w += qa.x * w4.w;
            acc[1].x += qa.y * w4.x; acc[1].y += qa.y * w4.y; acc[1].z += qa.y * w4.z; acc[1].w += qa.y * w4.w;
            acc[2].x += qa.z * w4.x; acc[2].y += qa.z * w4.y; acc[2].z += qa.z * w4.z; acc[2].w += qa.z * w4.w;
            acc[3].x += qa.w * w4.x; acc[3].y += qa.w * w4.y; acc[3].z += qa.w * w4.z; acc[3].w += qa.w * w4.w;
        }
#pragma unroll
        for (int rr = 0; rr < 4; rr++)
            *(float4*)&vss[(gR * 4 + rr) * 68 + c4 * 4] = acc[rr];
    }
    __syncthreads();

    // 64-row partial kv outer product: thread owns d-quad x e-quad
    const int d0 = (t >> 4) * 4, e0 = (t & 15) * 4;
    float4 a0 = {0,0,0,0}, a1 = {0,0,0,0}, a2 = {0,0,0,0}, a3 = {0,0,0,0};
#pragma unroll 4
    for (int i = 0; i < 64; i++) {
        float4 kk4 = *(const float4*)&kfs[i * 68 + d0];
        float4 v4 = *(const float4*)&vss[i * 68 + e0];
        a0.x += kk4.x * v4.x; a0.y += kk4.x * v4.y; a0.z += kk4.x * v4.z; a0.w += kk4.x * v4.w;
        a1.x += kk4.y * v4.x; a1.y += kk4.y * v4.y; a1.z += kk4.y * v4.z; a1.w += kk4.y * v4.w;
        a2.x += kk4.z * v4.x; a2.y += kk4.z * v4.y; a2.z += kk4.z * v4.z; a2.w += kk4.z * v4.w;
        a3.x += kk4.w * v4.x; a3.y += kk4.w * v4.y; a3.z += kk4.w * v4.z; a3.w += kk4.w * v4.w;
    }
    float* outp = kvp + (size_t)blk * 4096;   // blk == (b*4+h)*32 + ch
    *(float4*)(outp + (d0 + 0) * 64 + e0) = a0;
    *(float4*)(outp + (d0 + 1) * 64 + e0) = a1;
    *(float4*)(outp + (d0 + 2) * 64 + e0) = a2;
    *(float4*)(outp + (d0 + 3) * 64 + e0) = a3;
}

// ---------------------------------------------------------------------------
// k2b_reduce: 64 blocks x 256 thr.  blk = bh*4 + q; thread sums the 32
// partials for f4 index q*256 + t.  Kernel boundary provides cross-XCD
// visibility -- no fences, no atomics.
// ---------------------------------------------------------------------------
__global__ __launch_bounds__(256) void k2b_reduce(
    const float* __restrict__ kvp, float* __restrict__ kvg)
{
    const int blk = blockIdx.x, t = threadIdx.x;
    const int bh = blk >> 2, q = blk & 3;
    const int f4i = q * 256 + t;
    const float* src = kvp + (size_t)(bh * 32) * 4096 + f4i * 4;
    float4 s = {0.f, 0.f, 0.f, 0.f};
#pragma unroll
    for (int cc = 0; cc < 32; cc++) {
        float4 p = *(const float4*)(src + (size_t)cc * 4096);
        s.x += p.x; s.y += p.y; s.z += p.z; s.w += p.w;
    }
    *(float4*)(kvg + (size_t)bh * 4096 + f4i * 4) = s;
}

// ---------------------------------------------------------------------------
// k4_out: 512 blocks x 256 thr; block = 16 rows. (unchanged, proven)
// ---------------------------------------------------------------------------
__global__ __launch_bounds__(256) void k4_out(
    const float* __restrict__ g_ql, const float* __restrict__ w_high,
    const float* __restrict__ b_high, const float* __restrict__ zg,
    const float* __restrict__ kvg,
    const float* __restrict__ w_out_low, const float* __restrict__ b_out_low,
    const float* __restrict__ w_out_high, const float* __restrict__ b_out_high,
    float* __restrict__ out)
{
    __shared__ float bufW[24 * 260];   // w_high q^T; rows 0..15 reused as lin
    __shared__ float qfs[4 * 1092];    // [h][row 16][stride 68]
    __shared__ float qlT[24 * 16];
    __shared__ float lows[16 * 8];
    __shared__ float zs[64];
    float* lin = bufW;                 // alias: lin[16][260]

    const int t = threadIdx.x, blk = blockIdx.x;
    const int rowbase = blk * 16;
    const int b = blk >> 7;
    const float* kvb = kvg + (size_t)b * 4 * 4096;

    stage_whT(w_high, bufW, t);            // q-weights
    // stage qlT: 384 entries with 256 threads
    {
        int k = t >> 4, r = t & 15;
        qlT[t] = g_ql[(size_t)k * ROWS + rowbase + r];
        if (t < 128) {
            int idx2 = 256 + t;
            int k2 = idx2 >> 4, r2 = idx2 & 15;
            qlT[idx2] = g_ql[(size_t)k2 * ROWS + rowbase + r2];
        }
    }
    if (t < 64) zs[t] = zg[(size_t)rowbase * 4 + t];
    __syncthreads();

    const int wv = t >> 6, c = t & 63;
    const int h = c >> 4, e4 = c & 15;

    // phase 1: recompute qf rows wv*4..+3, cols j = c*4..+3 -> qfs[h][row][dl]
    {
        float4 bh4 = *(const float4*)(b_high + c * 4);
        float4 a0 = bh4, a1 = bh4, a2 = bh4, a3 = bh4;
#pragma unroll
        for (int k = 0; k < 24; k++) {
            float4 w4 = *(const float4*)&bufW[k * 260 + c * 4];
            float4 q4 = *(const float4*)&qlT[k * 16 + wv * 4];
            a0.x += q4.x * w4.x; a0.y += q4.x * w4.y; a0.z += q4.x * w4.z; a0.w += q4.x * w4.w;
            a1.x += q4.y * w4.x; a1.y += q4.y * w4.y; a1.z += q4.y * w4.z; a1.w += q4.y * w4.w;
            a2.x += q4.z * w4.x; a2.y += q4.z * w4.y; a2.z += q4.z * w4.z; a2.w += q4.z * w4.w;
            a3.x += q4.w * w4.x; a3.y += q4.w * w4.y; a3.z += q4.w * w4.z; a3.w += q4.w * w4.w;
        }
        float4 aa[4] = {a0, a1, a2, a3};
#pragma unroll
        for (int rr = 0; rr < 4; rr++) {
            float4 a = aa[rr];
            a.x = elu1(a.x); a.y = elu1(a.y); a.z = elu1(a.z); a.w = elu1(a.w);
            *(float4*)&qfs[h * 1092 + (wv * 4 + rr) * 68 + e4 * 4] = a;
        }
    }
    __syncthreads();   // qfs ready; bufW dead -> lin may be written

    // phase 2: lin[row][c*4..+3] = z * sum_d qf[row][h*64+d] * kv[h][d][e]
    {
        float4 acc[4] = {{0,0,0,0},{0,0,0,0},{0,0,0,0},{0,0,0,0}};
        const float* kvh = kvb + h * 4096 + e4 * 4;
        const float* qrow = &qfs[h * 1092 + (wv * 4) * 68];
#pragma unroll
        for (int d4 = 0; d4 < 16; d4++) {
            float4 k0 = *(const float4*)(kvh + (d4 * 4 + 0) * 64);
            float4 k1 = *(const float4*)(kvh + (d4 * 4 + 1) * 64);
            float4 k2 = *(const float4*)(kvh + (d4 * 4 + 2) * 64);
            float4 k3 = *(const float4*)(kvh + (d4 * 4 + 3) * 64);
#pragma unroll
            for (int rr = 0; rr < 4; rr++) {
                float4 qa = *(const float4*)(qrow + rr * 68 + d4 * 4);
                acc[rr].x += qa.x * k0.x + qa.y * k1.x + qa.z * k2.x + qa.w * k3.x;
                acc[rr].y += qa.x * k0.y + qa.y * k1.y + qa.z * k2.y + qa.w * k3.y;
                acc[rr].z += qa.x * k0.z + qa.y * k1.z + qa.z * k2.z + qa.w * k3.z;
                acc[rr].w += qa.x * k0.w + qa.y * k1.w + qa.z * k2.w + qa.w * k3.w;
            }
        }
#pragma unroll
        for (int rr = 0; rr < 4; rr++) {
            float zv = zs[(wv * 4 + rr) * 4 + h];
            *(float4*)&lin[(wv * 4 + rr) * 260 + c * 4] =
                make_float4(acc[rr].x * zv, acc[rr].y * zv,
                            acc[rr].z * zv, acc[rr].w * zv);
        }
    }
    __syncthreads();

    // phase 3: low projection (128 threads; 8-lane broadcast reads)
    if (t < 128) {
        int rr = t >> 3, j = t & 7;
        float a = b_out_low[j];
        const float4* wj = (const float4*)(w_out_low + j * H_);
#pragma unroll
        for (int kq = 0; kq < 64; kq++) {
            float4 l4 = *(const float4*)&lin[rr * 260 + kq * 4];
            float4 w4 = wj[kq];
            a += l4.x * w4.x + l4.y * w4.y + l4.z * w4.z + l4.w * w4.w;
        }
        lows[rr * 8 + j] = a;
    }
    __syncthreads();

    // phase 4: high projection, coalesced f4 stores
    {
        int rr = t >> 4, ig = t & 15;
        float l[8];
#pragma unroll
        for (int j = 0; j < 8; j++) l[j] = lows[rr * 8 + j];
        float* outp = out + (size_t)(rowbase + rr) * H_;
#pragma unroll
        for (int i16 = 0; i16 < 4; i16++) {
            int i = i16 * 64 + ig * 4;
            const float* wh = w_out_high + i * 8;
            float4 s;
            s.x = b_out_high[i + 0]; s.y = b_out_high[i + 1];
            s.z = b_out_high[i + 2]; s.w = b_out_high[i + 3];
#pragma unroll
            for (int j = 0; j < 8; j++) {
                s.x += l[j] * wh[j];
                s.y += l[j] * wh[8 + j];
                s.z += l[j] * wh[16 + j];
                s.w += l[j] * wh[24 + j];
            }
            *(float4*)(outp + i) = s;
        }
    }
}

extern "C" void kernel_launch(void* const* d_in, const int* in_sizes, int n_in,
                              void* d_out, int out_size, void* d_ws, size_t ws_size,
                              hipStream_t stream) {
    const float* x          = (const float*)d_in[0];
    const float* w_qkv_low  = (const float*)d_in[1];
    const float* b_qkv_low  = (const float*)d_in[2];
    const float* w_qkv_high = (const float*)d_in[3];
    const float* b_qkv_high = (const float*)d_in[4];
    const float* w_out_low  = (const float*)d_in[5];
    const float* b_out_low  = (const float*)d_in[6];
    const float* w_out_high = (const float*)d_in[7];
    const float* b_out_high = (const float*)d_in[8];
    // d_in[9] adj_u, d_in[10] adj_v: unused (attn_reg_loss is the constant REGW/N)
    char* wsb = (char*)d_ws;
    float* g_ql = (float*)(wsb);                          // 768 KB fp32 [24][8192]
    float* zg   = (float*)(wsb + ((size_t)0x100000));     // 128 KB fp32 [8192][4]
    float* kvg  = (float*)(wsb + ((size_t)0x140000));     // 256 KB fp32 [16][4096]
    float* kvp  = (float*)(wsb + ((size_t)0x200000));     // 8 MB  fp32 [512][4096]
    float* out = (float*)d_out;

    k1_qkv<<<512, 256, 0, stream>>>(x, w_qkv_low, b_qkv_low, w_qkv_high,
                                    b_qkv_high, g_ql, zg, kvp, out);
    k2b_reduce<<<64, 256, 0, stream>>>(kvp, kvg);
    k4_out<<<512, 256, 0, stream>>>(g_ql, w_qkv_high, b_qkv_high, zg, kvg,
                                    w_out_low, b_out_low, w_out_high,
                                    b_out_high, out);
}

// Round 8
// 125.533 us; speedup vs baseline: 1.2181x; 1.2181x over previous
//
#include <hip/hip_runtime.h>
#include <math.h>

// Problem constants
#define B_     4
#define N_     2048
#define H_     256
#define ROWS   8192    // B_*N_
#define EPS_   1e-8f
#define REGW   1e-5f
#define OUT_MAIN (ROWS*H_)   // 2097152

static __device__ __forceinline__ float elu1(float x) {
    return x > 0.f ? x + 1.f : __expf(x);
}

// stage + transpose a 256-row w_high chunk [256][24] -> dst[k*260 + j]
static __device__ __forceinline__ void stage_whT(
    const float* __restrict__ wsrc, float* __restrict__ dst, int t)
{
#pragma unroll
    for (int i = 0; i < 6; i++) {
        int g = t + i * 256;
        float4 v4 = *(const float4*)(wsrc + g * 4);
        int e = g * 4, j = e / 24, k = e - j * 24;
        dst[(k + 0) * 260 + j] = v4.x;
        dst[(k + 1) * 260 + j] = v4.y;
        dst[(k + 2) * 260 + j] = v4.z;
        dst[(k + 3) * 260 + j] = v4.w;
    }
}

// ---------------------------------------------------------------------------
// ka_ql: 512 blocks x 256 thr; block = 16 rows.  ql GEMM only. (round-6,
// proven)  Writes the constant reg-loss (softmax rows sum to 1 =>
// mean|attn| == 1/N, independent of adj_u/adj_v).
// ---------------------------------------------------------------------------
__global__ __launch_bounds__(256) void ka_ql(
    const float* __restrict__ x, const float* __restrict__ w_low,
    const float* __restrict__ b_low, float* __restrict__ g_ql,
    float* __restrict__ out)
{
    __shared__ float bufA[24 * 260];
    const int t = threadIdx.x;
    const size_t rowbase = (size_t)blockIdx.x * 16;
    const int rb = t >> 4, c4 = t & 15;

    if (blockIdx.x == 0 && t == 0)
        out[OUT_MAIN] = REGW / (float)N_;   // 4.8828125e-9

    // stage w_low [24][256] -> bufA[j*260+k] (straight copy)
#pragma unroll
    for (int i = 0; i < 6; i++) {
        int g = t + i * 256;
        int j = g >> 6, k = (g & 63) * 4;
        *(float4*)&bufA[j * 260 + k] = *(const float4*)(w_low + g * 4);
    }
    // x slice into registers (interleaved k-slices, coalesced)
    float4 xr[4];
#pragma unroll
    for (int i = 0; i < 4; i++)
        xr[i] = *(const float4*)(x + (rowbase + rb) * H_ + i * 64 + c4 * 4);
    __syncthreads();

    // ql[24] via 16-lane shfl reduce (all lanes of a row-group hold it all)
    float ql[24];
#pragma unroll
    for (int j = 0; j < 24; j++) {
        float s = 0.f;
#pragma unroll
        for (int i = 0; i < 4; i++) {
            float4 w4 = *(const float4*)&bufA[j * 260 + i * 64 + c4 * 4];
            s += xr[i].x * w4.x + xr[i].y * w4.y + xr[i].z * w4.z + xr[i].w * w4.w;
        }
        s += __shfl_xor(s, 1, 16);
        s += __shfl_xor(s, 2, 16);
        s += __shfl_xor(s, 4, 16);
        s += __shfl_xor(s, 8, 16);
        ql[j] = s + b_low[j];
    }
    // select lane-owned entries without dynamic register indexing (rule #20)
    float v1 = 0.f, v2 = 0.f;
#pragma unroll
    for (int j = 0; j < 16; j++) if (c4 == j) v1 = ql[j];
#pragma unroll
    for (int j = 0; j < 8; j++)  if (c4 == j) v2 = ql[16 + j];
    size_t row = rowbase + rb;
    g_ql[(size_t)c4 * ROWS + row] = v1;
    if (c4 < 8) g_ql[(size_t)(16 + c4) * ROWS + row] = v2;
}

// ---------------------------------------------------------------------------
// k2_kvz: grid 512 = b*128 + h*32 + ch; block = 64 rows of one head.
// (round-6, proven)  NO FENCES (round-5 lesson: per-block device fences
// serialize on L2 writeback).  Kernel boundary orders kvp for k2b.
// ---------------------------------------------------------------------------
__global__ __launch_bounds__(256) void k2_kvz(
    const float* __restrict__ g_ql, const float* __restrict__ w_high,
    const float* __restrict__ b_high, float* __restrict__ zg,
    float* __restrict__ kvp)
{
    __shared__ float wkT[24 * 64];    // [kk][d] k-weights^T for head h
    __shared__ float wvT[24 * 64];    // [kk][d] v-weights^T
    __shared__ float qls[24 * 64];    // [kk][r]
    __shared__ float kfs[64 * 68];    // [r][d] elu'd
    __shared__ float vss[64 * 68];    // [r][d]

    const int blk = blockIdx.x, t = threadIdx.x;
    const int b = blk >> 7, h = (blk >> 5) & 3, ch = blk & 31;
    const int rowb = b * N_ + ch * 64;

    // stage head-slices of w_high, coalesced f4 + transpose.
    // k-chunk base: (256 + h*64)*24 = 6144 + h*1536 ; v: 12288 + h*1536.
#pragma unroll
    for (int i = 0; i < 2; i++) {
        int g = t + i * 256;
        if (g < 384) {
            float4 a4 = *(const float4*)(w_high + 6144 + h * 1536 + g * 4);
            float4 b4 = *(const float4*)(w_high + 12288 + h * 1536 + g * 4);
            int e = g * 4, d = e / 24, kk = e - d * 24;
            wkT[(kk + 0) * 64 + d] = a4.x;
            wkT[(kk + 1) * 64 + d] = a4.y;
            wkT[(kk + 2) * 64 + d] = a4.z;
            wkT[(kk + 3) * 64 + d] = a4.w;
            wvT[(kk + 0) * 64 + d] = b4.x;
            wvT[(kk + 1) * 64 + d] = b4.y;
            wvT[(kk + 2) * 64 + d] = b4.z;
            wvT[(kk + 3) * 64 + d] = b4.w;
        }
    }
    // stage ql tile [24][64]: 384 f4s -> two guarded passes
#pragma unroll
    for (int i = 0; i < 2; i++) {
        int g = t + i * 256;
        if (g < 384) {
            int kk = g >> 4, r4 = g & 15;
            *(float4*)&qls[kk * 64 + r4 * 4] =
                *(const float4*)(g_ql + (size_t)kk * ROWS + rowb + r4 * 4);
        }
    }
    __syncthreads();

    const int gR = t >> 4, c4 = t & 15;   // 16 row-groups(4 rows) x 16 col-quads

    // kf tile (+ z): rows gR*4..+3, cols c4*4..+3
    {
        float4 bh4 = *(const float4*)(b_high + 256 + h * 64 + c4 * 4);
        float4 acc[4];
#pragma unroll
        for (int rr = 0; rr < 4; rr++) acc[rr] = bh4;
#pragma unroll
        for (int kk = 0; kk < 24; kk++) {
            float4 w4 = *(const float4*)&wkT[kk * 64 + c4 * 4];
            float4 qa = *(const float4*)&qls[kk * 64 + gR * 4];
            acc[0].x += qa.x * w4.x; acc[0].y += qa.x * w4.y; acc[0].z += qa.x * w4.z; acc[0].w += qa.x * w4.w;
            acc[1].x += qa.y * w4.x; acc[1].y += qa.y * w4.y; acc[1].z += qa.y * w4.z; acc[1].w += qa.y * w4.w;
            acc[2].x += qa.z * w4.x; acc[2].y += qa.z * w4.y; acc[2].z += qa.z * w4.z; acc[2].w += qa.z * w4.w;
            acc[3].x += qa.w * w4.x; acc[3].y += qa.w * w4.y; acc[3].z += qa.w * w4.z; acc[3].w += qa.w * w4.w;
        }
#pragma unroll
        for (int rr = 0; rr < 4; rr++) {
            float4 a = acc[rr];
            a.x = elu1(a.x); a.y = elu1(a.y); a.z = elu1(a.z); a.w = elu1(a.w);
            *(float4*)&kfs[(gR * 4 + rr) * 68 + c4 * 4] = a;
            float s = a.x + a.y + a.z + a.w;
            s += __shfl_xor(s, 1, 16);
            s += __shfl_xor(s, 2, 16);
            s += __shfl_xor(s, 4, 16);
            s += __shfl_xor(s, 8, 16);
            if (c4 == 0)
                zg[(size_t)(rowb + gR * 4 + rr) * 4 + h] = 1.f / (s + EPS_);
        }
    }
    // v tile
    {
        float4 bh4 = *(const float4*)(b_high + 512 + h * 64 + c4 * 4);
        float4 acc[4];
#pragma unroll
        for (int rr = 0; rr < 4; rr++) acc[rr] = bh4;
#pragma unroll
        for (int kk = 0; kk < 24; kk++) {
            float4 w4 = *(const float4*)&wvT[kk * 64 + c4 * 4];
            float4 qa = *(const float4*)&qls[kk * 64 + gR * 4];
            acc[0].x += qa.x * w4.x; acc[0].y += qa.x * w4.y; acc[0].z += qa.x * w4.z; acc[0].w += qa.x * w4.w;
            acc[1].x += qa.y * w4.x; acc[1].y += qa.y * w4.y; acc[1].z += qa.y * w4.z; acc[1].w += qa.y * w4.w;
            acc[2].x += qa.z * w4.x; acc[2].y += qa.z * w4.y; acc[2].z += qa.z * w4.z; acc[2].w += qa.z * w4.w;
            acc[3].x += qa.w * w4.x; acc[3].y += qa.w * w4.y; acc[3].z += qa.w * w4.z; acc[3].w += qa.w * w4.w;
        }
#pragma unroll
        for (int rr = 0; rr < 4; rr++)
            *(float4*)&vss[(gR * 4 + rr) * 68 + c4 * 4] = acc[rr];
    }
    __syncthreads();

    // 64-row partial kv outer product: thread owns d-quad x e-quad
    const int d0 = (t >> 4) * 4, e0 = (t & 15) * 4;
    float4 a0 = {0,0,0,0}, a1 = {0,0,0,0}, a2 = {0,0,0,0}, a3 = {0,0,0,0};
#pragma unroll 4
    for (int i = 0; i < 64; i++) {
        float4 kk4 = *(const float4*)&kfs[i * 68 + d0];
        float4 v4 = *(const float4*)&vss[i * 68 + e0];
        a0.x += kk4.x * v4.x; a0.y += kk4.x * v4.y; a0.z += kk4.x * v4.z; a0.w += kk4.x * v4.w;
        a1.x += kk4.y * v4.x; a1.y += kk4.y * v4.y; a1.z += kk4.y * v4.z; a1.w += kk4.y * v4.w;
        a2.x += kk4.z * v4.x; a2.y += kk4.z * v4.y; a2.z += kk4.z * v4.z; a2.w += kk4.z * v4.w;
        a3.x += kk4.w * v4.x; a3.y += kk4.w * v4.y; a3.z += kk4.w * v4.z; a3.w += kk4.w * v4.w;
    }
    float* outp = kvp + (size_t)blk * 4096;   // blk == bh*32 + ch
    *(float4*)(outp + (d0 + 0) * 64 + e0) = a0;
    *(float4*)(outp + (d0 + 1) * 64 + e0) = a1;
    *(float4*)(outp + (d0 + 2) * 64 + e0) = a2;
    *(float4*)(outp + (d0 + 3) * 64 + e0) = a3;
}

// ---------------------------------------------------------------------------
// k2b_reduce: 64 blocks x 256 thr.  blk = bh*4 + q; thread sums the 32
// partials for f4 index q*256 + t.  Kernel boundary provides cross-XCD
// visibility -- no fences, no atomics.  (round-6, proven)
// ---------------------------------------------------------------------------
__global__ __launch_bounds__(256) void k2b_reduce(
    const float* __restrict__ kvp, float* __restrict__ kvg)
{
    const int blk = blockIdx.x, t = threadIdx.x;
    const int bh = blk >> 2, q = blk & 3;
    const int f4i = q * 256 + t;
    const float* src = kvp + (size_t)(bh * 32) * 4096 + f4i * 4;
    float4 s = {0.f, 0.f, 0.f, 0.f};
#pragma unroll
    for (int cc = 0; cc < 32; cc++) {
        float4 p = *(const float4*)(src + (size_t)cc * 4096);
        s.x += p.x; s.y += p.y; s.z += p.z; s.w += p.w;
    }
    *(float4*)(kvg + (size_t)bh * 4096 + f4i * 4) = s;
}

// ---------------------------------------------------------------------------
// k4_out (OCCUPANCY SPLIT): 1024 blocks x 256 thr; block = 8 rows.
// Round-6 k4 was grid-limited to 2 blocks/CU (512 blocks, 44.7 KB LDS) ->
// 2 waves/SIMD, ~90% latency stall.  8-row blocks: LDS ~35.4 KB (qfs
// halves, lin aliases bufW) -> 4 blocks/CU, grid 1024 = exactly 4/CU =
// 16 waves/CU.  acc arrays halve -> VGPR <= 128 keeps 4 blocks resident.
// qfs head-stride 548 (mod 32 = 4) keeps h-groups bank-staggered.
// ---------------------------------------------------------------------------
__global__ __launch_bounds__(256) void k4_out(
    const float* __restrict__ g_ql, const float* __restrict__ w_high,
    const float* __restrict__ b_high, const float* __restrict__ zg,
    const float* __restrict__ kvg,
    const float* __restrict__ w_out_low, const float* __restrict__ b_out_low,
    const float* __restrict__ w_out_high, const float* __restrict__ b_out_high,
    float* __restrict__ out)
{
    __shared__ float bufW[24 * 260];   // w_high q^T; rows 0..7 reused as lin
    __shared__ float qfs[4 * 548];     // [h][row 8][stride 68], head stride 548
    __shared__ float qlT[24 * 8];
    __shared__ float lows[8 * 8];
    __shared__ float zs[32];
    float* lin = bufW;                 // alias: lin[8][260]

    const int t = threadIdx.x, blk = blockIdx.x;
    const int rowbase = blk * 8;
    const int b = blk >> 8;
    const float* kvb = kvg + (size_t)b * 4 * 4096;

    stage_whT(w_high, bufW, t);            // q-weights
    if (t < 192) {                          // qlT [24][8]
        int k = t >> 3, r = t & 7;
        qlT[t] = g_ql[(size_t)k * ROWS + rowbase + r];
    }
    if (t < 32) zs[t] = zg[(size_t)rowbase * 4 + t];
    __syncthreads();

    const int wv = t >> 6, c = t & 63;
    const int h = c >> 4, e4 = c & 15;
    const int r0 = wv * 2;                 // 2 rows per thread, 8 per block

    // phase 1: recompute qf rows r0..r0+1, cols j = c*4..+3
    {
        float4 bh4 = *(const float4*)(b_high + c * 4);
        float4 a0 = bh4, a1 = bh4;
#pragma unroll
        for (int k = 0; k < 24; k++) {
            float4 w4 = *(const float4*)&bufW[k * 260 + c * 4];
            float2 q2 = *(const float2*)&qlT[k * 8 + r0];
            a0.x += q2.x * w4.x; a0.y += q2.x * w4.y; a0.z += q2.x * w4.z; a0.w += q2.x * w4.w;
            a1.x += q2.y * w4.x; a1.y += q2.y * w4.y; a1.z += q2.y * w4.z; a1.w += q2.y * w4.w;
        }
        a0.x = elu1(a0.x); a0.y = elu1(a0.y); a0.z = elu1(a0.z); a0.w = elu1(a0.w);
        a1.x = elu1(a1.x); a1.y = elu1(a1.y); a1.z = elu1(a1.z); a1.w = elu1(a1.w);
        *(float4*)&qfs[h * 548 + (r0 + 0) * 68 + e4 * 4] = a0;
        *(float4*)&qfs[h * 548 + (r0 + 1) * 68 + e4 * 4] = a1;
    }
    __syncthreads();   // qfs ready; bufW dead -> lin may be written

    // phase 2: lin[row][c*4..+3] = z * sum_d qf[row][h*64+d] * kv[h][d][e]
    {
        float4 acc0 = {0,0,0,0}, acc1 = {0,0,0,0};
        const float* kvh = kvb + h * 4096 + e4 * 4;
        const float* qrow = &qfs[h * 548 + r0 * 68];
#pragma unroll
        for (int d4 = 0; d4 < 16; d4++) {
            float4 k0 = *(const float4*)(kvh + (d4 * 4 + 0) * 64);
            float4 k1 = *(const float4*)(kvh + (d4 * 4 + 1) * 64);
            float4 k2 = *(const float4*)(kvh + (d4 * 4 + 2) * 64);
            float4 k3 = *(const float4*)(kvh + (d4 * 4 + 3) * 64);
            float4 qa = *(const float4*)(qrow + d4 * 4);
            float4 qb = *(const float4*)(qrow + 68 + d4 * 4);
            acc0.x += qa.x * k0.x + qa.y * k1.x + qa.z * k2.x + qa.w * k3.x;
            acc0.y += qa.x * k0.y + qa.y * k1.y + qa.z * k2.y + qa.w * k3.y;
            acc0.z += qa.x * k0.z + qa.y * k1.z + qa.z * k2.z + qa.w * k3.z;
            acc0.w += qa.x * k0.w + qa.y * k1.w + qa.z * k2.w + qa.w * k3.w;
            acc1.x += qb.x * k0.x + qb.y * k1.x + qb.z * k2.x + qb.w * k3.x;
            acc1.y += qb.x * k0.y + qb.y * k1.y + qb.z * k2.y + qb.w * k3.y;
            acc1.z += qb.x * k0.z + qb.y * k1.z + qb.z * k2.z + qb.w * k3.z;
            acc1.w += qb.x * k0.w + qb.y * k1.w + qb.z * k2.w + qb.w * k3.w;
        }
        float z0 = zs[(r0 + 0) * 4 + h];
        float z1 = zs[(r0 + 1) * 4 + h];
        *(float4*)&lin[(r0 + 0) * 260 + c * 4] =
            make_float4(acc0.x * z0, acc0.y * z0, acc0.z * z0, acc0.w * z0);
        *(float4*)&lin[(r0 + 1) * 260 + c * 4] =
            make_float4(acc1.x * z1, acc1.y * z1, acc1.z * z1, acc1.w * z1);
    }
    __syncthreads();

    // phase 3: low projection (64 threads; 8-lane broadcast reads)
    if (t < 64) {
        int rr = t >> 3, j = t & 7;
        float a = b_out_low[j];
        const float4* wj = (const float4*)(w_out_low + j * H_);
#pragma unroll
        for (int kq = 0; kq < 64; kq++) {
            float4 l4 = *(const float4*)&lin[rr * 260 + kq * 4];
            float4 w4 = wj[kq];
            a += l4.x * w4.x + l4.y * w4.y + l4.z * w4.z + l4.w * w4.w;
        }
        lows[rr * 8 + j] = a;
    }
    __syncthreads();

    // phase 4: high projection, coalesced f4 stores (8 rows x 32 col-quads)
    {
        int rr = t >> 5, ig = t & 31;
        float l[8];
#pragma unroll
        for (int j = 0; j < 8; j++) l[j] = lows[rr * 8 + j];
        float* outp = out + (size_t)(rowbase + rr) * H_;
#pragma unroll
        for (int i32 = 0; i32 < 2; i32++) {
            int i = i32 * 128 + ig * 4;
            const float* wh = w_out_high + i * 8;
            float4 s;
            s.x = b_out_high[i + 0]; s.y = b_out_high[i + 1];
            s.z = b_out_high[i + 2]; s.w = b_out_high[i + 3];
#pragma unroll
            for (int j = 0; j < 8; j++) {
                s.x += l[j] * wh[j];
                s.y += l[j] * wh[8 + j];
                s.z += l[j] * wh[16 + j];
                s.w += l[j] * wh[24 + j];
            }
            *(float4*)(outp + i) = s;
        }
    }
}

extern "C" void kernel_launch(void* const* d_in, const int* in_sizes, int n_in,
                              void* d_out, int out_size, void* d_ws, size_t ws_size,
                              hipStream_t stream) {
    const float* x          = (const float*)d_in[0];
    const float* w_qkv_low  = (const float*)d_in[1];
    const float* b_qkv_low  = (const float*)d_in[2];
    const float* w_qkv_high = (const float*)d_in[3];
    const float* b_qkv_high = (const float*)d_in[4];
    const float* w_out_low  = (const float*)d_in[5];
    const float* b_out_low  = (const float*)d_in[6];
    const float* w_out_high = (const float*)d_in[7];
    const float* b_out_high = (const float*)d_in[8];
    // d_in[9] adj_u, d_in[10] adj_v: unused (attn_reg_loss is the constant REGW/N)
    char* wsb = (char*)d_ws;
    float* g_ql = (float*)(wsb);                          // 768 KB fp32 [24][8192]
    float* zg   = (float*)(wsb + ((size_t)0x100000));     // 128 KB fp32 [8192][4]
    float* kvg  = (float*)(wsb + ((size_t)0x140000));     // 256 KB fp32 [16][4096]
    float* kvp  = (float*)(wsb + ((size_t)0x200000));     // 8 MB  fp32 [512][4096]
    float* out = (float*)d_out;

    ka_ql<<<512, 256, 0, stream>>>(x, w_qkv_low, b_qkv_low, g_ql, out);
    k2_kvz<<<512, 256, 0, stream>>>(g_ql, w_qkv_high, b_qkv_high, zg, kvp);
    k2b_reduce<<<64, 256, 0, stream>>>(kvp, kvg);
    k4_out<<<1024, 256, 0, stream>>>(g_ql, w_qkv_high, b_qkv_high, zg, kvg,
                                     w_out_low, b_out_low, w_out_high,
                                     b_out_high, out);
}